// Round 1
// baseline (195.233 us; speedup 1.0000x reference)
//
#include <hip/hip_runtime.h>
#include <hip/hip_bf16.h>

// MoE top-2 dispatch -> pair-binned grouped GEMM (bf16 MFMA) -> single-store combine.
// Pipeline per launch (all on `stream`):
//   1. memset cnt[64]
//   2. cvt_x_pair : xs1 = bf16(g1*x), xs2 = bf16(g2*x)   (gates folded into A)
//   3. cvt_wt     : Wt[e][o][d] = bf16(W[e][d][o])       (transpose for k-contig B frags)
//   4. route_pairs: bin tokens by (e1,e2) pair; idx/gp lists via atomics
//   5. finalize   : prefix tiles -> tmap (<=192 m-tile slots, exact)
//   6. moe_gemm   : 128x128 tile, 4 waves, BK=64, two K=1024 passes (W[e1], W[e2])
//                   into one accumulator; plain f32 stores (each out row written once).

#define TOK 16384
#define DD  1024
#define OO  1024
#define NE  8
#define NBIN 64
#define MAXT 192   // sum ceil(cnt_p/128) <= 128 + 63 < 192
#define BM  128
#define BN  128
#define BK  64

typedef __bf16 bf16x8 __attribute__((ext_vector_type(8)));
typedef float  f32x4  __attribute__((ext_vector_type(4)));

__device__ __forceinline__ unsigned short f2bf(float f) {
  unsigned u = __float_as_uint(f);
  u += 0x7fffu + ((u >> 16) & 1u);   // RNE
  return (unsigned short)(u >> 16);
}

__device__ __forceinline__ void gload_lds16(const void* g, void* l) {
  __builtin_amdgcn_global_load_lds(
      (const __attribute__((address_space(1))) void*)g,
      (__attribute__((address_space(3))) void*)l, 16, 0, 0);
}

// ---------------- convert x with gates folded in ----------------
__global__ __launch_bounds__(256) void cvt_x_pair(
    const float* __restrict__ x, const float* __restrict__ gates,
    unsigned short* __restrict__ xs1, unsigned short* __restrict__ xs2) {
  int gid = blockIdx.x * 256 + threadIdx.x;   // one thread = 8 elems; 128 threads/token
  int tok = gid >> 7;
  float g1 = 0.f, g2 = 0.f; int seen = 0;
#pragma unroll
  for (int e = 0; e < NE; ++e) {
    float g = gates[tok * NE + e];
    if (g > 0.f) { if (seen == 0) g1 = g; else if (seen == 1) g2 = g; ++seen; }
  }
  const float4* xp = (const float4*)x + (size_t)gid * 2;
  float4 u = xp[0], v = xp[1];
  float uu[8] = {u.x, u.y, u.z, u.w, v.x, v.y, v.z, v.w};
  alignas(16) unsigned short o1[8];
  alignas(16) unsigned short o2[8];
#pragma unroll
  for (int j = 0; j < 8; ++j) { o1[j] = f2bf(uu[j] * g1); o2[j] = f2bf(uu[j] * g2); }
  *(uint4*)(xs1 + (size_t)gid * 8) = *(const uint4*)o1;
  *(uint4*)(xs2 + (size_t)gid * 8) = *(const uint4*)o2;
}

// ---------------- transpose + convert W ----------------
__global__ __launch_bounds__(256) void cvt_wt(
    const float* __restrict__ W, unsigned short* __restrict__ Wt) {
  __shared__ float tile[64][65];
  int e = blockIdx.z, d0 = blockIdx.y * 64, o0 = blockIdx.x * 64;
  const float* src = W + ((size_t)e << 20) + (size_t)d0 * OO + o0;
  for (int i = threadIdx.x; i < 4096; i += 256) {
    int r = i >> 6, c = i & 63;
    tile[r][c] = src[(size_t)r * OO + c];
  }
  __syncthreads();
  unsigned short* dst = Wt + ((size_t)e << 20) + (size_t)o0 * DD + d0;
  for (int i = threadIdx.x; i < 4096; i += 256) {
    int r = i >> 6, c = i & 63;
    dst[(size_t)r * DD + c] = f2bf(tile[c][r]);
  }
}

// ---------------- routing: bin by expert pair ----------------
__global__ __launch_bounds__(256) void route_pairs(
    const float* __restrict__ gates, int* __restrict__ cnt,
    int* __restrict__ idx, float2* __restrict__ gp) {
  int i = blockIdx.x * 256 + threadIdx.x;
  if (i >= TOK) return;
  int e1 = -1, e2 = -1; float g1 = 0.f, g2 = 0.f;
#pragma unroll
  for (int e = 0; e < NE; ++e) {
    float g = gates[i * NE + e];
    if (g > 0.f) { if (e1 < 0) { e1 = e; g1 = g; } else if (e2 < 0) { e2 = e; g2 = g; } }
  }
  if (e1 < 0) return;                       // no routing (impossible for softmax gates)
  if (e2 < 0) { e2 = e1; g2 = 0.f; }        // single-expert token: xs2 row is zero anyway
  int pid = e1 * NE + e2;
  int pos = atomicAdd(cnt + pid, 1);
  idx[pid * TOK + pos] = i;
  gp[(size_t)pid * TOK + pos] = make_float2(g1, g2);
}

// ---------------- tile map ----------------
__global__ void finalize(const int* __restrict__ cnt, int* __restrict__ tmap) {
  if (threadIdx.x == 0) {
    int t = 0;
    for (int p = 0; p < NBIN; ++p) {
      int n = (cnt[p] + BM - 1) >> 7;
      for (int k = 0; k < n && t < MAXT; ++k) { tmap[t] = p; tmap[MAXT + t] = k; ++t; }
    }
    for (; t < MAXT; ++t) tmap[t] = -1;
  }
}

// ---------------- grouped GEMM ----------------
__global__ __launch_bounds__(256) void moe_gemm(
    const unsigned short* __restrict__ xs1, const unsigned short* __restrict__ xs2,
    const unsigned short* __restrict__ wtb, const int* __restrict__ idx,
    const float2* __restrict__ gp, const int* __restrict__ cnt,
    const int* __restrict__ tmap, const float* __restrict__ bias,
    float* __restrict__ out) {
  __shared__ unsigned short As[BM * BK];
  __shared__ unsigned short Bs[BN * BK];
  __shared__ int   rowsS[BM];
  __shared__ float2 gS[BM];

  int slotT = blockIdx.y;
  int pid = tmap[slotT];
  if (pid < 0) return;
  int lt = tmap[MAXT + slotT];
  int e1 = pid >> 3, e2 = pid & 7;
  int cntv = cnt[pid];
  int n0 = blockIdx.x * BN;

  int t = threadIdx.x, lane = t & 63, w = t >> 6;
  if (t < BM) {
    int slot = lt * BM + t;
    int tok = 0; float2 g = make_float2(0.f, 0.f);
    if (slot < cntv) { tok = idx[pid * TOK + slot]; g = gp[(size_t)pid * TOK + slot]; }
    rowsS[t] = tok; gS[t] = g;
  }
  __syncthreads();

  // staging source pointers (pre-swizzled global column so linear LDS dest +
  // swizzled ds_read form the same involution; chunk ^= (row&7))
  const unsigned short* aP[4];
  const unsigned short* bP[4];
  int c0 = (lane & 7) << 3;
#pragma unroll
  for (int it = 0; it < 4; ++it) {
    int r = (w * 4 + it) * 8 + (lane >> 3);        // tile row this lane stages
    int csrc = (((c0 >> 3) ^ (r & 7)) << 3);
    aP[it] = xs1 + (size_t)rowsS[r] * DD + csrc;
    bP[it] = wtb + ((size_t)e1 * OO + n0 + r) * DD + csrc;
  }
  const size_t aAdv = (size_t)TOK * DD;                     // xs1 -> xs2
  const ptrdiff_t bAdv = (ptrdiff_t)(e2 - e1) * OO * DD;    // W[e1] -> W[e2]

  int wm = w >> 1, wn = w & 1;
  int hi = lane >> 4, lo = lane & 15;
  int aOff[4][2], bOff[4][2];
#pragma unroll
  for (int m = 0; m < 4; ++m) {
    int arow = wm * 64 + m * 16 + lo;
    int brow = wn * 64 + m * 16 + lo;
#pragma unroll
    for (int ks = 0; ks < 2; ++ks) {
      aOff[m][ks] = arow * BK + ((((ks << 2) + hi) ^ (arow & 7)) << 3);
      bOff[m][ks] = brow * BK + ((((ks << 2) + hi) ^ (brow & 7)) << 3);
    }
  }

  f32x4 acc[4][4] = {};

#pragma unroll 1
  for (int pass = 0; pass < 2; ++pass) {
#pragma unroll 1
    for (int k0 = 0; k0 < DD; k0 += BK) {
#pragma unroll
      for (int it = 0; it < 4; ++it) {
        gload_lds16(aP[it] + k0, As + (((w << 2) + it) << 9));
        gload_lds16(bP[it] + k0, Bs + (((w << 2) + it) << 9));
      }
      __syncthreads();   // compiler drains vmcnt before s_barrier
#pragma unroll
      for (int ks = 0; ks < 2; ++ks) {
        bf16x8 af[4], bfr[4];
#pragma unroll
        for (int m = 0; m < 4; ++m) af[m] = *(const bf16x8*)(As + aOff[m][ks]);
#pragma unroll
        for (int n = 0; n < 4; ++n) bfr[n] = *(const bf16x8*)(Bs + bOff[n][ks]);
#pragma unroll
        for (int m = 0; m < 4; ++m)
#pragma unroll
          for (int n = 0; n < 4; ++n)
            acc[m][n] = __builtin_amdgcn_mfma_f32_16x16x32_bf16(af[m], bfr[n], acc[m][n], 0, 0, 0);
      }
      __syncthreads();
    }
    if (pass == 0) {
#pragma unroll
      for (int it = 0; it < 4; ++it) { aP[it] += aAdv; bP[it] += bAdv; }
    }
  }

  // epilogue: gates already folded into A; add gated bias; plain stores
  const float* b1 = bias + e1 * OO;
  const float* b2 = bias + e2 * OO;
  float b1v[4], b2v[4];
#pragma unroll
  for (int n = 0; n < 4; ++n) {
    int col = n0 + wn * 64 + n * 16 + lo;
    b1v[n] = b1[col]; b2v[n] = b2[col];
  }
#pragma unroll
  for (int m = 0; m < 4; ++m) {
#pragma unroll
    for (int j = 0; j < 4; ++j) {
      int rl = wm * 64 + m * 16 + hi * 4 + j;   // C/D layout: row=(lane>>4)*4+reg, col=lane&15
      int slot = lt * BM + rl;
      if (slot < cntv) {
        int tok = rowsS[rl];
        float2 g = gS[rl];
        float* orow = out + (size_t)tok * OO + n0 + wn * 64 + lo;
#pragma unroll
        for (int n = 0; n < 4; ++n)
          orow[n * 16] = acc[m][n][j] + g.x * b1v[n] + g.y * b2v[n];
      }
    }
  }
}

extern "C" void kernel_launch(void* const* d_in, const int* in_sizes, int n_in,
                              void* d_out, int out_size, void* d_ws, size_t ws_size,
                              hipStream_t stream) {
  const float* x     = (const float*)d_in[0];
  const float* gates = (const float*)d_in[1];
  const float* W     = (const float*)d_in[2];
  const float* bias  = (const float*)d_in[3];
  float* out = (float*)d_out;

  char* ws = (char*)d_ws;
  size_t off = 0;
  unsigned short* xs1 = (unsigned short*)(ws + off); off += (size_t)TOK * DD * 2;
  unsigned short* xs2 = (unsigned short*)(ws + off); off += (size_t)TOK * DD * 2;
  unsigned short* wtb = (unsigned short*)(ws + off); off += (size_t)NE * DD * OO * 2;
  int*    idx  = (int*)(ws + off);    off += (size_t)NBIN * TOK * 4;
  float2* gp   = (float2*)(ws + off); off += (size_t)NBIN * TOK * 8;
  int*    cnt  = (int*)(ws + off);    off += NBIN * 4;
  int*    tmap = (int*)(ws + off);    off += 2 * MAXT * 4;
  if (ws_size < off) return;  // insufficient scratch (needs ~92.5 MB) — fail visibly

  hipMemsetAsync(cnt, 0, NBIN * 4, stream);
  cvt_x_pair<<<(TOK * DD) / (256 * 8), 256, 0, stream>>>(x, gates, xs1, xs2);
  dim3 gw(OO / 64, DD / 64, NE);
  cvt_wt<<<gw, 256, 0, stream>>>(W, wtb);
  route_pairs<<<TOK / 256, 256, 0, stream>>>(gates, cnt, idx, gp);
  finalize<<<1, 64, 0, stream>>>(cnt, tmap);
  dim3 gg(OO / BN, MAXT, 1);
  moe_gemm<<<gg, 256, 0, stream>>>(xs1, xs2, wtb, idx, gp, cnt, tmap, bias, out);
}

// Round 2
// 178.297 us; speedup vs baseline: 1.0950x; 1.0950x over previous
//
#include <hip/hip_runtime.h>
#include <hip/hip_bf16.h>

// MoE top-2 dispatch -> pair-binned grouped GEMM (bf16 MFMA) -> single-store combine.
//   1. memset cnt[64]
//   2. cvt_x     : xs = bf16(x)                  (gates folded via acc-rescale in GEMM)
//   3. cvt_wt    : Wt[e][o][d] = bf16(W[e][d][o])
//   4. route_pairs: bin tokens by (e1,e2); store (r=g1/g2, s=g2) per slot
//   5. finalize  : counts -> tile map (BM=160 rows/tile)
//   6. moe_gemm  : 160x128 tile, 4 waves, BK=64, pass0 = x*W[e1]; acc *= r;
//                  pass1 += x*W[e2]; out = s*(acc + r*b1 + b2). Single store/row.
// BM=160 keeps tile-jobs J ~= 830-1050 <= 2*capacity -> exactly 2 dispatch rounds
// (the round-quantization that capped the previous version at 70% efficiency).

#define TOK 16384
#define DD  1024
#define OO  1024
#define NE  8
#define NBIN 64
#define MAXT 160   // nT = sum ceil(cnt_p/160) <= 103+28 = 131 < 160
#define BM  160
#define BN  128
#define BK  64

typedef __bf16 bf16x8 __attribute__((ext_vector_type(8)));
typedef float  f32x4  __attribute__((ext_vector_type(4)));

__device__ __forceinline__ unsigned short f2bf(float f) {
  unsigned u = __float_as_uint(f);
  u += 0x7fffu + ((u >> 16) & 1u);   // RNE
  return (unsigned short)(u >> 16);
}

__device__ __forceinline__ void gload_lds16(const void* g, void* l) {
  __builtin_amdgcn_global_load_lds(
      (const __attribute__((address_space(1))) void*)g,
      (__attribute__((address_space(3))) void*)l, 16, 0, 0);
}

// ---------------- convert x -> bf16 (no gates) ----------------
__global__ __launch_bounds__(256) void cvt_x(
    const float* __restrict__ x, unsigned short* __restrict__ xs) {
  int gid = blockIdx.x * 256 + threadIdx.x;   // one thread = 8 elems
  const float4* xp = (const float4*)x + (size_t)gid * 2;
  float4 u = xp[0], v = xp[1];
  float uu[8] = {u.x, u.y, u.z, u.w, v.x, v.y, v.z, v.w};
  alignas(16) unsigned short o[8];
#pragma unroll
  for (int j = 0; j < 8; ++j) o[j] = f2bf(uu[j]);
  *(uint4*)(xs + (size_t)gid * 8) = *(const uint4*)o;
}

// ---------------- transpose + convert W ----------------
__global__ __launch_bounds__(256) void cvt_wt(
    const float* __restrict__ W, unsigned short* __restrict__ Wt) {
  __shared__ float tile[64][65];
  int e = blockIdx.z, d0 = blockIdx.y * 64, o0 = blockIdx.x * 64;
  const float* src = W + ((size_t)e << 20) + (size_t)d0 * OO + o0;
  for (int i = threadIdx.x; i < 4096; i += 256) {
    int r = i >> 6, c = i & 63;
    tile[r][c] = src[(size_t)r * OO + c];
  }
  __syncthreads();
  unsigned short* dst = Wt + ((size_t)e << 20) + (size_t)o0 * DD + d0;
  for (int i = threadIdx.x; i < 4096; i += 256) {
    int r = i >> 6, c = i & 63;
    dst[(size_t)r * DD + c] = f2bf(tile[c][r]);
  }
}

// ---------------- routing: bin by expert pair ----------------
__global__ __launch_bounds__(256) void route_pairs(
    const float* __restrict__ gates, int* __restrict__ cnt,
    int* __restrict__ idx, float2* __restrict__ gp) {
  int i = blockIdx.x * 256 + threadIdx.x;
  if (i >= TOK) return;
  int e1 = -1, e2 = -1; float g1 = 0.f, g2 = 0.f;
#pragma unroll
  for (int e = 0; e < NE; ++e) {
    float g = gates[i * NE + e];
    if (g > 0.f) { if (e1 < 0) { e1 = e; g1 = g; } else if (e2 < 0) { e2 = e; g2 = g; } }
  }
  if (e1 < 0) return;
  float r, s;
  if (e2 < 0) { e2 = e1; r = 1.f; s = 0.5f * g1; }   // single-expert: (r=1,s=g1/2)
  else        { r = g1 / g2; s = g2; }
  int pid = e1 * NE + e2;
  int pos = atomicAdd(cnt + pid, 1);
  idx[pid * TOK + pos] = i;
  gp[(size_t)pid * TOK + pos] = make_float2(r, s);
}

// ---------------- tile map ----------------
__global__ void finalize(const int* __restrict__ cnt, int* __restrict__ tmap) {
  if (threadIdx.x == 0) {
    int t = 0;
    for (int p = 0; p < NBIN; ++p) {
      int n = (cnt[p] + BM - 1) / BM;
      for (int k = 0; k < n && t < MAXT; ++k) { tmap[t] = p; tmap[MAXT + t] = k; ++t; }
    }
    for (; t < MAXT; ++t) tmap[t] = -1;
  }
}

// ---------------- grouped GEMM ----------------
__global__ __launch_bounds__(256) void moe_gemm(
    const unsigned short* __restrict__ xs,
    const unsigned short* __restrict__ wtb, const int* __restrict__ idx,
    const float2* __restrict__ gp, const int* __restrict__ cnt,
    const int* __restrict__ tmap, const float* __restrict__ bias,
    float* __restrict__ out) {
  __shared__ unsigned short As[BM * BK];   // 20 KB
  __shared__ unsigned short Bs[BN * BK];   // 16 KB
  __shared__ int    rowsS[BM];
  __shared__ float2 gS[BM];

  int slotT = blockIdx.y;
  int pid = tmap[slotT];
  if (pid < 0) return;
  int lt = tmap[MAXT + slotT];
  int e1 = pid >> 3, e2 = pid & 7;
  int cntv = cnt[pid];
  int n0 = blockIdx.x * BN;

  int t = threadIdx.x, lane = t & 63, w = t >> 6;
  if (t < BM) {
    int slot = lt * BM + t;
    int tok = 0; float2 g = make_float2(0.f, 0.f);
    if (slot < cntv) { tok = idx[pid * TOK + slot]; g = gp[(size_t)pid * TOK + slot]; }
    rowsS[t] = tok; gS[t] = g;
  }
  __syncthreads();

  // staging source pointers (pre-swizzled global column: linear LDS dest +
  // swizzled ds_read form the same involution; chunk ^= (row&7))
  const unsigned short* aP[5];
  const unsigned short* bP[4];
  int c0 = (lane & 7) << 3;
  int csrc = (((c0 >> 3) ^ (lane >> 3)) << 3);   // staged rows have row&7 == lane>>3
#pragma unroll
  for (int it = 0; it < 5; ++it) {
    int r = (w * 5 + it) * 8 + (lane >> 3);      // A tile row this lane stages (<160)
    aP[it] = xs + (size_t)rowsS[r] * DD + csrc;
  }
#pragma unroll
  for (int it = 0; it < 4; ++it) {
    int r = (w * 4 + it) * 8 + (lane >> 3);      // B tile row (<128)
    bP[it] = wtb + ((size_t)e1 * OO + n0 + r) * DD + csrc;
  }
  const ptrdiff_t bAdv = (ptrdiff_t)(e2 - e1) * OO * DD;    // W[e1] -> W[e2]

  int wm = w >> 1, wn = w & 1;
  int hi = lane >> 4, lo = lane & 15;
  int aOff[5][2], bOff[4][2];
#pragma unroll
  for (int m = 0; m < 5; ++m) {
    int arow = wm * 80 + m * 16 + lo;
#pragma unroll
    for (int ks = 0; ks < 2; ++ks)
      aOff[m][ks] = arow * BK + ((((ks << 2) + hi) ^ (arow & 7)) << 3);
  }
#pragma unroll
  for (int n = 0; n < 4; ++n) {
    int brow = wn * 64 + n * 16 + lo;
#pragma unroll
    for (int ks = 0; ks < 2; ++ks)
      bOff[n][ks] = brow * BK + ((((ks << 2) + hi) ^ (brow & 7)) << 3);
  }

  f32x4 acc[5][4] = {};

#pragma unroll 1
  for (int pass = 0; pass < 2; ++pass) {
#pragma unroll 1
    for (int k0 = 0; k0 < DD; k0 += BK) {
#pragma unroll
      for (int it = 0; it < 5; ++it)
        gload_lds16(aP[it] + k0, As + (((w * 5) + it) << 9));
#pragma unroll
      for (int it = 0; it < 4; ++it)
        gload_lds16(bP[it] + k0, Bs + (((w << 2) + it) << 9));
      __syncthreads();   // compiler drains vmcnt before s_barrier
#pragma unroll
      for (int ks = 0; ks < 2; ++ks) {
        bf16x8 af[5], bfr[4];
#pragma unroll
        for (int m = 0; m < 5; ++m) af[m] = *(const bf16x8*)(As + aOff[m][ks]);
#pragma unroll
        for (int n = 0; n < 4; ++n) bfr[n] = *(const bf16x8*)(Bs + bOff[n][ks]);
#pragma unroll
        for (int m = 0; m < 5; ++m)
#pragma unroll
          for (int n = 0; n < 4; ++n)
            acc[m][n] = __builtin_amdgcn_mfma_f32_16x16x32_bf16(af[m], bfr[n], acc[m][n], 0, 0, 0);
      }
      __syncthreads();
    }
    if (pass == 0) {
#pragma unroll
      for (int it = 0; it < 4; ++it) bP[it] += bAdv;
      // rescale acc by r = g1/g2 per output row: acc := r*x*W1, pass1 adds x*W2
#pragma unroll
      for (int m = 0; m < 5; ++m) {
        float rr[4];
#pragma unroll
        for (int j = 0; j < 4; ++j) rr[j] = gS[wm * 80 + m * 16 + hi * 4 + j].x;
#pragma unroll
        for (int n = 0; n < 4; ++n)
#pragma unroll
          for (int j = 0; j < 4; ++j) acc[m][n][j] *= rr[j];
      }
    }
  }

  // epilogue: out = s*(acc + r*b1 + b2)
  const float* b1 = bias + e1 * OO;
  const float* b2 = bias + e2 * OO;
  float b1v[4], b2v[4];
#pragma unroll
  for (int n = 0; n < 4; ++n) {
    int col = n0 + wn * 64 + n * 16 + lo;
    b1v[n] = b1[col]; b2v[n] = b2[col];
  }
#pragma unroll
  for (int m = 0; m < 5; ++m) {
#pragma unroll
    for (int j = 0; j < 4; ++j) {
      int rl = wm * 80 + m * 16 + hi * 4 + j;   // C/D: row=(lane>>4)*4+reg, col=lane&15
      int slot = lt * BM + rl;
      if (slot < cntv) {
        float2 g = gS[rl];
        float* orow = out + (size_t)rowsS[rl] * OO + n0 + wn * 64 + lo;
#pragma unroll
        for (int n = 0; n < 4; ++n)
          orow[n * 16] = g.y * (acc[m][n][j] + g.x * b1v[n] + b2v[n]);
      }
    }
  }
}

extern "C" void kernel_launch(void* const* d_in, const int* in_sizes, int n_in,
                              void* d_out, int out_size, void* d_ws, size_t ws_size,
                              hipStream_t stream) {
  const float* x     = (const float*)d_in[0];
  const float* gates = (const float*)d_in[1];
  const float* W     = (const float*)d_in[2];
  const float* bias  = (const float*)d_in[3];
  float* out = (float*)d_out;

  char* ws = (char*)d_ws;
  size_t off = 0;
  unsigned short* xs  = (unsigned short*)(ws + off); off += (size_t)TOK * DD * 2;
  unsigned short* wtb = (unsigned short*)(ws + off); off += (size_t)NE * DD * OO * 2;
  int*    idx  = (int*)(ws + off);    off += (size_t)NBIN * TOK * 4;
  float2* gp   = (float2*)(ws + off); off += (size_t)NBIN * TOK * 8;
  int*    cnt  = (int*)(ws + off);    off += NBIN * 4;
  int*    tmap = (int*)(ws + off);    off += 2 * MAXT * 4;
  if (ws_size < off) return;  // insufficient scratch (~60.5 MB needed)

  hipMemsetAsync(cnt, 0, NBIN * 4, stream);
  cvt_x<<<(TOK * DD) / (256 * 8), 256, 0, stream>>>(x, xs);
  dim3 gw(OO / 64, DD / 64, NE);
  cvt_wt<<<gw, 256, 0, stream>>>(W, wtb);
  route_pairs<<<TOK / 256, 256, 0, stream>>>(gates, cnt, idx, gp);
  finalize<<<1, 64, 0, stream>>>(cnt, tmap);
  dim3 gg(OO / BN, MAXT, 1);
  moe_gemm<<<gg, 256, 0, stream>>>(xs, wtb, idx, gp, cnt, tmap, bias, out);
}

// Round 3
// 161.389 us; speedup vs baseline: 1.2097x; 1.1048x over previous
//
#include <hip/hip_runtime.h>
#include <hip/hip_bf16.h>

// MoE top-2 dispatch -> pair-binned grouped GEMM (bf16 MFMA) -> single-store combine.
// 3 launches total:
//   0. memsetAsync cnt[64]
//   1. prep (fused, role-split by blockIdx.x):
//        blocks [0,64)      route: bin tokens by (e1,e2); store (r=g1/g2, s=g2)
//        blocks [64,4160)   cvt_x: xs = bf16(x), 16 elems/thread
//        blocks [4160,6208) cvt_wt: Wt[e][o][d] = bf16(W[e][d][o]) via LDS transpose
//   2. moe_gemm: derives its (pid, tile) from cnt[] via wave prefix-scan (no tmap
//      kernel); 160x128 tile, 4 waves, BK=64, pass0 = x*W[e1]; acc *= r;
//      pass1 += x*W[e2]; out = s*(acc + r*b1 + b2). Each out row stored once.

#define TOK 16384
#define DD  1024
#define OO  1024
#define NE  8
#define NBIN 64
#define MAXT 168   // hard bound: sum ceil(cnt_p/160) <= 16384/160 + 64 = 166
#define BM  160
#define BN  128
#define BK  64

typedef __bf16 bf16x8 __attribute__((ext_vector_type(8)));
typedef float  f32x4  __attribute__((ext_vector_type(4)));

__device__ __forceinline__ unsigned short f2bf(float f) {
  unsigned u = __float_as_uint(f);
  u += 0x7fffu + ((u >> 16) & 1u);   // RNE
  return (unsigned short)(u >> 16);
}

__device__ __forceinline__ void gload_lds16(const void* g, void* l) {
  __builtin_amdgcn_global_load_lds(
      (const __attribute__((address_space(1))) void*)g,
      (__attribute__((address_space(3))) void*)l, 16, 0, 0);
}

// ---------------- fused prep ----------------
#define PREP_ROUTE_B 64
#define PREP_CVTX_B  4096   // 16.7M elems / (256 thr * 16 elems)
#define PREP_CVTW_B  2048   // 8 experts * 16*16 tiles of 64x64

__global__ __launch_bounds__(256) void prep(
    const float* __restrict__ x, const float* __restrict__ gates,
    const float* __restrict__ W,
    unsigned short* __restrict__ xs, unsigned short* __restrict__ wtb,
    int* __restrict__ cnt, int* __restrict__ idx, float2* __restrict__ gp) {
  __shared__ float tile[64][65];
  int bid = blockIdx.x;

  if (bid < PREP_ROUTE_B) {
    // ---- route: one token per thread ----
    int i = bid * 256 + threadIdx.x;
    int e1 = -1, e2 = -1; float g1 = 0.f, g2 = 0.f;
#pragma unroll
    for (int e = 0; e < NE; ++e) {
      float g = gates[i * NE + e];
      if (g > 0.f) { if (e1 < 0) { e1 = e; g1 = g; } else if (e2 < 0) { e2 = e; g2 = g; } }
    }
    if (e1 < 0) return;
    float r, s;
    if (e2 < 0) { e2 = e1; r = 1.f; s = 0.5f * g1; }   // single-expert: (r=1, s=g1/2)
    else        { r = g1 / g2; s = g2; }
    int pid = e1 * NE + e2;
    int pos = atomicAdd(cnt + pid, 1);
    idx[pid * TOK + pos] = i;
    gp[(size_t)pid * TOK + pos] = make_float2(r, s);

  } else if (bid < PREP_ROUTE_B + PREP_CVTX_B) {
    // ---- cvt_x: 16 elems per thread ----
    size_t gid = (size_t)(bid - PREP_ROUTE_B) * 256 + threadIdx.x;
    const float4* xp = (const float4*)x + gid * 4;
    float4 v[4] = {xp[0], xp[1], xp[2], xp[3]};
    alignas(16) unsigned short o[16];
#pragma unroll
    for (int q = 0; q < 4; ++q) {
      o[q * 4 + 0] = f2bf(v[q].x); o[q * 4 + 1] = f2bf(v[q].y);
      o[q * 4 + 2] = f2bf(v[q].z); o[q * 4 + 3] = f2bf(v[q].w);
    }
    uint4* dst = (uint4*)(xs + gid * 16);
    dst[0] = *(const uint4*)(o + 0);
    dst[1] = *(const uint4*)(o + 8);

  } else {
    // ---- cvt_wt: 64x64 transpose tile, float4 loads, ushort4 stores ----
    int wb = bid - (PREP_ROUTE_B + PREP_CVTX_B);
    int e = wb >> 8, tt = wb & 255;
    int d0 = (tt >> 4) * 64, o0 = (tt & 15) * 64;
    const float* src = W + ((size_t)e << 20) + (size_t)d0 * OO + o0;
    for (int i = threadIdx.x; i < 1024; i += 256) {
      int r = i >> 4, c4 = (i & 15) * 4;
      float4 v = *(const float4*)(src + (size_t)r * OO + c4);
      tile[r][c4 + 0] = v.x; tile[r][c4 + 1] = v.y;
      tile[r][c4 + 2] = v.z; tile[r][c4 + 3] = v.w;
    }
    __syncthreads();
    unsigned short* dst = wtb + ((size_t)e << 20) + (size_t)o0 * DD + d0;
    for (int i = threadIdx.x; i < 1024; i += 256) {
      int o = i >> 4, d4 = (i & 15) * 4;
      alignas(8) unsigned short w4[4];
#pragma unroll
      for (int j = 0; j < 4; ++j) w4[j] = f2bf(tile[d4 + j][o]);
      *(ushort2*)(dst + (size_t)o * DD + d4) = *(const ushort2*)w4;       // lo 2
      *(ushort2*)(dst + (size_t)o * DD + d4 + 2) = *(const ushort2*)(w4 + 2);
    }
  }
}

// ---------------- grouped GEMM ----------------
__global__ __launch_bounds__(256) void moe_gemm(
    const unsigned short* __restrict__ xs,
    const unsigned short* __restrict__ wtb, const int* __restrict__ idx,
    const float2* __restrict__ gp, const int* __restrict__ cnt,
    const float* __restrict__ bias, float* __restrict__ out) {
  __shared__ unsigned short As[BM * BK];   // 20 KB
  __shared__ unsigned short Bs[BN * BK];   // 16 KB
  __shared__ int    rowsS[BM];
  __shared__ float2 gS[BM];
  __shared__ int    sPid, sLt, sCnt;

  // derive (pid, local tile) from cnt[] with a 64-lane prefix scan
  if (threadIdx.x < 64) {
    int lane = threadIdx.x;
    if (lane == 0) sPid = -1;
    int c = cnt[lane];
    int n = (c + BM - 1) / BM;
    int pre = n;
#pragma unroll
    for (int o = 1; o < 64; o <<= 1) {
      int v = __shfl_up(pre, o);
      if (lane >= o) pre += v;
    }
    int lo = pre - n;
    int tb = blockIdx.y;
    if (tb >= lo && tb < pre) { sPid = lane; sLt = tb - lo; sCnt = c; }
  }
  __syncthreads();
  int pid = sPid;
  if (pid < 0) return;
  int lt = sLt, cntv = sCnt;
  int e1 = pid >> 3, e2 = pid & 7;
  int n0 = blockIdx.x * BN;

  int t = threadIdx.x, lane = t & 63, w = t >> 6;
  if (t < BM) {
    int slot = lt * BM + t;
    int tok = 0; float2 g = make_float2(0.f, 0.f);
    if (slot < cntv) { tok = idx[pid * TOK + slot]; g = gp[(size_t)pid * TOK + slot]; }
    rowsS[t] = tok; gS[t] = g;
  }
  __syncthreads();

  // staging source pointers (pre-swizzled global column: linear LDS dest +
  // swizzled ds_read form the same involution; chunk ^= (row&7))
  const unsigned short* aP[5];
  const unsigned short* bP[4];
  int c0 = (lane & 7) << 3;
  int csrc = (((c0 >> 3) ^ (lane >> 3)) << 3);   // staged rows have row&7 == lane>>3
#pragma unroll
  for (int it = 0; it < 5; ++it) {
    int r = (w * 5 + it) * 8 + (lane >> 3);      // A tile row this lane stages (<160)
    aP[it] = xs + (size_t)rowsS[r] * DD + csrc;
  }
#pragma unroll
  for (int it = 0; it < 4; ++it) {
    int r = (w * 4 + it) * 8 + (lane >> 3);      // B tile row (<128)
    bP[it] = wtb + ((size_t)e1 * OO + n0 + r) * DD + csrc;
  }
  const ptrdiff_t bAdv = (ptrdiff_t)(e2 - e1) * OO * DD;    // W[e1] -> W[e2]

  int wm = w >> 1, wn = w & 1;
  int hi = lane >> 4, lo = lane & 15;
  int aOff[5][2], bOff[4][2];
#pragma unroll
  for (int m = 0; m < 5; ++m) {
    int arow = wm * 80 + m * 16 + lo;
#pragma unroll
    for (int ks = 0; ks < 2; ++ks)
      aOff[m][ks] = arow * BK + ((((ks << 2) + hi) ^ (arow & 7)) << 3);
  }
#pragma unroll
  for (int n = 0; n < 4; ++n) {
    int brow = wn * 64 + n * 16 + lo;
#pragma unroll
    for (int ks = 0; ks < 2; ++ks)
      bOff[n][ks] = brow * BK + ((((ks << 2) + hi) ^ (brow & 7)) << 3);
  }

  f32x4 acc[5][4] = {};

#pragma unroll 1
  for (int pass = 0; pass < 2; ++pass) {
#pragma unroll 1
    for (int k0 = 0; k0 < DD; k0 += BK) {
#pragma unroll
      for (int it = 0; it < 5; ++it)
        gload_lds16(aP[it] + k0, As + (((w * 5) + it) << 9));
#pragma unroll
      for (int it = 0; it < 4; ++it)
        gload_lds16(bP[it] + k0, Bs + (((w << 2) + it) << 9));
      __syncthreads();   // compiler drains vmcnt before s_barrier
#pragma unroll
      for (int ks = 0; ks < 2; ++ks) {
        bf16x8 af[5], bfr[4];
#pragma unroll
        for (int m = 0; m < 5; ++m) af[m] = *(const bf16x8*)(As + aOff[m][ks]);
#pragma unroll
        for (int n = 0; n < 4; ++n) bfr[n] = *(const bf16x8*)(Bs + bOff[n][ks]);
#pragma unroll
        for (int m = 0; m < 5; ++m)
#pragma unroll
          for (int n = 0; n < 4; ++n)
            acc[m][n] = __builtin_amdgcn_mfma_f32_16x16x32_bf16(af[m], bfr[n], acc[m][n], 0, 0, 0);
      }
      __syncthreads();
    }
    if (pass == 0) {
#pragma unroll
      for (int it = 0; it < 4; ++it) bP[it] += bAdv;
      // rescale acc by r = g1/g2 per output row: acc := r*x*W1, pass1 adds x*W2
#pragma unroll
      for (int m = 0; m < 5; ++m) {
        float rr[4];
#pragma unroll
        for (int j = 0; j < 4; ++j) rr[j] = gS[wm * 80 + m * 16 + hi * 4 + j].x;
#pragma unroll
        for (int n = 0; n < 4; ++n)
#pragma unroll
          for (int j = 0; j < 4; ++j) acc[m][n][j] *= rr[j];
      }
    }
  }

  // epilogue: out = s*(acc + r*b1 + b2)
  const float* b1 = bias + e1 * OO;
  const float* b2 = bias + e2 * OO;
  float b1v[4], b2v[4];
#pragma unroll
  for (int n = 0; n < 4; ++n) {
    int col = n0 + wn * 64 + n * 16 + lo;
    b1v[n] = b1[col]; b2v[n] = b2[col];
  }
#pragma unroll
  for (int m = 0; m < 5; ++m) {
#pragma unroll
    for (int j = 0; j < 4; ++j) {
      int rl = wm * 80 + m * 16 + hi * 4 + j;   // C/D: row=(lane>>4)*4+reg, col=lane&15
      int slot = lt * BM + rl;
      if (slot < cntv) {
        float2 g = gS[rl];
        float* orow = out + (size_t)rowsS[rl] * OO + n0 + wn * 64 + lo;
#pragma unroll
        for (int n = 0; n < 4; ++n)
          orow[n * 16] = g.y * (acc[m][n][j] + g.x * b1v[n] + b2v[n]);
      }
    }
  }
}

extern "C" void kernel_launch(void* const* d_in, const int* in_sizes, int n_in,
                              void* d_out, int out_size, void* d_ws, size_t ws_size,
                              hipStream_t stream) {
  const float* x     = (const float*)d_in[0];
  const float* gates = (const float*)d_in[1];
  const float* W     = (const float*)d_in[2];
  const float* bias  = (const float*)d_in[3];
  float* out = (float*)d_out;

  char* ws = (char*)d_ws;
  size_t off = 0;
  unsigned short* xs  = (unsigned short*)(ws + off); off += (size_t)TOK * DD * 2;
  unsigned short* wtb = (unsigned short*)(ws + off); off += (size_t)NE * DD * OO * 2;
  int*    idx  = (int*)(ws + off);    off += (size_t)NBIN * TOK * 4;
  float2* gp   = (float2*)(ws + off); off += (size_t)NBIN * TOK * 8;
  int*    cnt  = (int*)(ws + off);    off += NBIN * 4;
  if (ws_size < off) return;  // insufficient scratch (~60.5 MB needed)

  hipMemsetAsync(cnt, 0, NBIN * 4, stream);
  prep<<<PREP_ROUTE_B + PREP_CVTX_B + PREP_CVTW_B, 256, 0, stream>>>(
      x, gates, W, xs, wtb, cnt, idx, gp);
  dim3 gg(OO / BN, MAXT, 1);
  moe_gemm<<<gg, 256, 0, stream>>>(xs, wtb, idx, gp, cnt, bias, out);
}

// Round 4
// 153.260 us; speedup vs baseline: 1.2739x; 1.0530x over previous
//
#include <hip/hip_runtime.h>
#include <hip/hip_bf16.h>

// MoE top-2 dispatch -> pair-binned grouped GEMM (bf16 MFMA) -> single-store combine.
// 3 launches:
//   0. memsetAsync cnt[64]
//   1. prep (role-split): route | cvt_x (bf16, coalesced) | cvt_wt (transpose, 16B stores)
//   2. moe_gemm: derives (pid,tile) from cnt[] via wave prefix-scan.
//      160x128 tile, 4 waves, BK=64, DOUBLE-BUFFERED k-loop (one barrier per
//      k-step; STAGE(g+1) issued after the barrier, overlapped with MFMA(g)).
//      grid=(MAXT,8): 168%8==0 so the 8 col-blocks of a tile share an XCD ->
//      A-tile fetched once per XCD L2 instead of 8x from HBM.
//      pass0 = x*W[e1]; acc *= r=g1/g2; pass1 += x*W[e2]; out = s*(acc+r*b1+b2).

#define TOK 16384
#define DD  1024
#define OO  1024
#define NE  8
#define NBIN 64
#define MAXT 168   // hard bound: sum ceil(cnt_p/160) <= 16384/160 + 64 = 166; 168%8==0
#define BM  160
#define BN  128
#define BK  64

typedef __bf16 bf16x8 __attribute__((ext_vector_type(8)));
typedef float  f32x4  __attribute__((ext_vector_type(4)));

__device__ __forceinline__ unsigned short f2bf(float f) {
  unsigned u = __float_as_uint(f);
  u += 0x7fffu + ((u >> 16) & 1u);   // RNE
  return (unsigned short)(u >> 16);
}

__device__ __forceinline__ void gload_lds16(const void* g, void* l) {
  __builtin_amdgcn_global_load_lds(
      (const __attribute__((address_space(1))) void*)g,
      (__attribute__((address_space(3))) void*)l, 16, 0, 0);
}

// ---------------- fused prep ----------------
#define PREP_ROUTE_B 64
#define PREP_CVTX_B  4096   // 4.19M float4 / (256 thr * 4)
#define PREP_CVTW_B  2048   // 8 experts * 256 tiles of 64x64

__global__ __launch_bounds__(256) void prep(
    const float* __restrict__ x, const float* __restrict__ gates,
    const float* __restrict__ W,
    unsigned short* __restrict__ xs, unsigned short* __restrict__ wtb,
    int* __restrict__ cnt, int* __restrict__ idx, float2* __restrict__ gp) {
  __shared__ float tile[64][65];
  int bid = blockIdx.x;

  if (bid < PREP_ROUTE_B) {
    // ---- route: one token per thread ----
    int i = bid * 256 + threadIdx.x;
    int e1 = -1, e2 = -1; float g1 = 0.f, g2 = 0.f;
#pragma unroll
    for (int e = 0; e < NE; ++e) {
      float g = gates[i * NE + e];
      if (g > 0.f) { if (e1 < 0) { e1 = e; g1 = g; } else if (e2 < 0) { e2 = e; g2 = g; } }
    }
    if (e1 < 0) return;
    float r, s;
    if (e2 < 0) { e2 = e1; r = 1.f; s = 0.5f * g1; }   // single-expert: (r=1, s=g1/2)
    else        { r = g1 / g2; s = g2; }
    int pid = e1 * NE + e2;
    int pos = atomicAdd(cnt + pid, 1);
    idx[pid * TOK + pos] = i;
    gp[(size_t)pid * TOK + pos] = make_float2(r, s);

  } else if (bid < PREP_ROUTE_B + PREP_CVTX_B) {
    // ---- cvt_x: 16 elems/thread, per-instruction coalesced (16B ld / 8B st) ----
    size_t base = (size_t)(bid - PREP_ROUTE_B) * 1024 + threadIdx.x;  // float4 units
    const float4* xp = (const float4*)x;
#pragma unroll
    for (int q = 0; q < 4; ++q) {
      float4 v = xp[base + q * 256];
      alignas(8) unsigned short o4[4] = {f2bf(v.x), f2bf(v.y), f2bf(v.z), f2bf(v.w)};
      *(uint2*)(xs + (base + q * 256) * 4) = *(const uint2*)o4;
    }

  } else {
    // ---- cvt_wt: 64x64 transpose tile; float4 loads, 16B stores ----
    int wb = bid - (PREP_ROUTE_B + PREP_CVTX_B);
    int e = wb >> 8, tt = wb & 255;
    int d0 = (tt >> 4) * 64, o0 = (tt & 15) * 64;
    const float* src = W + ((size_t)e << 20) + (size_t)d0 * OO + o0;
    for (int i = threadIdx.x; i < 1024; i += 256) {
      int r = i >> 4, c4 = (i & 15) * 4;
      float4 v = *(const float4*)(src + (size_t)r * OO + c4);
      tile[r][c4 + 0] = v.x; tile[r][c4 + 1] = v.y;
      tile[r][c4 + 2] = v.z; tile[r][c4 + 3] = v.w;
    }
    __syncthreads();
    unsigned short* dst = wtb + ((size_t)e << 20) + (size_t)o0 * DD + d0;
    for (int i = threadIdx.x; i < 512; i += 256) {
      int o = i >> 3, d8 = (i & 7) * 8;
      alignas(16) unsigned short w8[8];
#pragma unroll
      for (int j = 0; j < 8; ++j) w8[j] = f2bf(tile[d8 + j][o]);
      *(uint4*)(dst + (size_t)o * DD + d8) = *(const uint4*)w8;
    }
  }
}

// ---------------- grouped GEMM ----------------
__global__ __launch_bounds__(256) void moe_gemm(
    const unsigned short* __restrict__ xs,
    const unsigned short* __restrict__ wtb, const int* __restrict__ idx,
    const float2* __restrict__ gp, const int* __restrict__ cnt,
    const float* __restrict__ bias, float* __restrict__ out) {
  __shared__ unsigned short As[2 * BM * BK];   // 40 KB (double-buffered)
  __shared__ unsigned short Bs[2 * BN * BK];   // 32 KB
  __shared__ int    rowsS[BM];
  __shared__ float2 gS[BM];
  __shared__ int    sPid, sLt, sCnt;

  // derive (pid, local tile) from cnt[] with a 64-lane prefix scan
  if (threadIdx.x < 64) {
    int lane = threadIdx.x;
    if (lane == 0) sPid = -1;
    int c = cnt[lane];
    int n = (c + BM - 1) / BM;
    int pre = n;
#pragma unroll
    for (int o = 1; o < 64; o <<= 1) {
      int v = __shfl_up(pre, o);
      if (lane >= o) pre += v;
    }
    int lo = pre - n;
    int tb = blockIdx.x;                      // grid.x = tile index now
    if (tb >= lo && tb < pre) { sPid = lane; sLt = tb - lo; sCnt = c; }
  }
  __syncthreads();
  int pid = sPid;
  if (pid < 0) return;
  int lt = sLt, cntv = sCnt;
  int e1 = pid >> 3, e2 = pid & 7;
  int n0 = blockIdx.y * BN;                   // grid.y = output column block

  int t = threadIdx.x, lane = t & 63, w = t >> 6;
  if (t < BM) {
    int slot = lt * BM + t;
    int tok = 0; float2 g = make_float2(0.f, 0.f);
    if (slot < cntv) { tok = idx[pid * TOK + slot]; g = gp[(size_t)pid * TOK + slot]; }
    rowsS[t] = tok; gS[t] = g;
  }
  __syncthreads();

  // staging source pointers (pre-swizzled global column: linear LDS dest +
  // swizzled ds_read form the same involution; chunk ^= (row&7))
  const unsigned short* aP[5];
  const unsigned short* bP[4];
  int csrc = ((((lane & 7)) ^ (lane >> 3)) << 3);   // staged rows have row&7 == lane>>3
#pragma unroll
  for (int it = 0; it < 5; ++it) {
    int r = (w * 5 + it) * 8 + (lane >> 3);      // A tile row this lane stages (<160)
    aP[it] = xs + (size_t)rowsS[r] * DD + csrc;
  }
#pragma unroll
  for (int it = 0; it < 4; ++it) {
    int r = (w * 4 + it) * 8 + (lane >> 3);      // B tile row (<128)
    bP[it] = wtb + ((size_t)e1 * OO + n0 + r) * DD + csrc;
  }
  const ptrdiff_t bAdv = (ptrdiff_t)(e2 - e1) * OO * DD;    // W[e1] -> W[e2]

  int wm = w >> 1, wn = w & 1;
  int hi = lane >> 4, lo = lane & 15;
  int aOff[5][2], bOff[4][2];
#pragma unroll
  for (int m = 0; m < 5; ++m) {
    int arow = wm * 80 + m * 16 + lo;
#pragma unroll
    for (int ks = 0; ks < 2; ++ks)
      aOff[m][ks] = arow * BK + ((((ks << 2) + hi) ^ (arow & 7)) << 3);
  }
#pragma unroll
  for (int n = 0; n < 4; ++n) {
    int brow = wn * 64 + n * 16 + lo;
#pragma unroll
    for (int ks = 0; ks < 2; ++ks)
      bOff[n][ks] = brow * BK + ((((ks << 2) + hi) ^ (brow & 7)) << 3);
  }

  // stage k-step g (g in [0,32): pass = g>>4, k0 = (g&15)*64) into buffer buf
  auto STAGE = [&](int g, int buf) {
    int k0 = (g & 15) << 6;
    int aB = buf * (BM * BK), bB = buf * (BN * BK);
    const ptrdiff_t badd = (g & 16) ? bAdv : 0;
#pragma unroll
    for (int it = 0; it < 5; ++it)
      gload_lds16(aP[it] + k0, As + aB + (((w * 5) + it) << 9));
#pragma unroll
    for (int it = 0; it < 4; ++it)
      gload_lds16(bP[it] + badd + k0, Bs + bB + (((w << 2) + it) << 9));
  };

  f32x4 acc[5][4] = {};

  STAGE(0, 0);
#pragma unroll 1
  for (int g = 0; g < 32; ++g) {
    int cur = g & 1;
    __syncthreads();                 // drains STAGE(g); prefetch from g-1 landed
    if (g < 31) STAGE(g + 1, cur ^ 1);   // in flight across this step's MFMAs
    int aB = cur * (BM * BK), bB = cur * (BN * BK);
#pragma unroll
    for (int ks = 0; ks < 2; ++ks) {
      bf16x8 af[5], bfr[4];
#pragma unroll
      for (int m = 0; m < 5; ++m) af[m] = *(const bf16x8*)(As + aB + aOff[m][ks]);
#pragma unroll
      for (int n = 0; n < 4; ++n) bfr[n] = *(const bf16x8*)(Bs + bB + bOff[n][ks]);
#pragma unroll
      for (int m = 0; m < 5; ++m)
#pragma unroll
        for (int n = 0; n < 4; ++n)
          acc[m][n] = __builtin_amdgcn_mfma_f32_16x16x32_bf16(af[m], bfr[n], acc[m][n], 0, 0, 0);
    }
    if (g == 15) {
      // pass boundary: acc := r*(x*W1); pass1 adds x*W2
#pragma unroll
      for (int m = 0; m < 5; ++m) {
        float rr[4];
#pragma unroll
        for (int j = 0; j < 4; ++j) rr[j] = gS[wm * 80 + m * 16 + hi * 4 + j].x;
#pragma unroll
        for (int n = 0; n < 4; ++n)
#pragma unroll
          for (int j = 0; j < 4; ++j) acc[m][n][j] *= rr[j];
      }
    }
  }

  // epilogue: out = s*(acc + r*b1 + b2)
  const float* b1 = bias + e1 * OO;
  const float* b2 = bias + e2 * OO;
  float b1v[4], b2v[4];
#pragma unroll
  for (int n = 0; n < 4; ++n) {
    int col = n0 + wn * 64 + n * 16 + lo;
    b1v[n] = b1[col]; b2v[n] = b2[col];
  }
#pragma unroll
  for (int m = 0; m < 5; ++m) {
#pragma unroll
    for (int j = 0; j < 4; ++j) {
      int rl = wm * 80 + m * 16 + hi * 4 + j;   // C/D: row=(lane>>4)*4+reg, col=lane&15
      int slot = lt * BM + rl;
      if (slot < cntv) {
        float2 g = gS[rl];
        float* orow = out + (size_t)rowsS[rl] * OO + n0 + wn * 64 + lo;
#pragma unroll
        for (int n = 0; n < 4; ++n)
          orow[n * 16] = g.y * (acc[m][n][j] + g.x * b1v[n] + b2v[n]);
      }
    }
  }
}

extern "C" void kernel_launch(void* const* d_in, const int* in_sizes, int n_in,
                              void* d_out, int out_size, void* d_ws, size_t ws_size,
                              hipStream_t stream) {
  const float* x     = (const float*)d_in[0];
  const float* gates = (const float*)d_in[1];
  const float* W     = (const float*)d_in[2];
  const float* bias  = (const float*)d_in[3];
  float* out = (float*)d_out;

  char* ws = (char*)d_ws;
  size_t off = 0;
  unsigned short* xs  = (unsigned short*)(ws + off); off += (size_t)TOK * DD * 2;
  unsigned short* wtb = (unsigned short*)(ws + off); off += (size_t)NE * DD * OO * 2;
  int*    idx  = (int*)(ws + off);    off += (size_t)NBIN * TOK * 4;
  float2* gp   = (float2*)(ws + off); off += (size_t)NBIN * TOK * 8;
  int*    cnt  = (int*)(ws + off);    off += NBIN * 4;
  if (ws_size < off) return;  // insufficient scratch (~60.5 MB needed)

  hipMemsetAsync(cnt, 0, NBIN * 4, stream);
  prep<<<PREP_ROUTE_B + PREP_CVTX_B + PREP_CVTW_B, 256, 0, stream>>>(
      x, gates, W, xs, wtb, cnt, idx, gp);
  dim3 gg(MAXT, OO / BN, 1);   // tile index in x: 168%8==0 -> col-blocks share XCD
  moe_gemm<<<gg, 256, 0, stream>>>(xs, wtb, idx, gp, cnt, bias, out);
}